// Round 1
// baseline (443.857 us; speedup 1.0000x reference)
//
#include <hip/hip_runtime.h>

#define T_TOK  2048
#define DIMD   1024
#define INTERI 512
#define NEXP   16
#define NSEG   17   // 16 routed + 1 shared (index 16)

typedef __bf16 bf16x8 __attribute__((ext_vector_type(8)));
typedef float  f32x4  __attribute__((ext_vector_type(4)));

// ---------- helpers ----------
__device__ __forceinline__ unsigned short f2b(float f) {
    union { float f; unsigned int u; } c; c.f = f;
    unsigned int u = c.u;
    unsigned int r = (u + 0x7FFFu + ((u >> 16) & 1u)) >> 16;  // RNE
    return (unsigned short)r;
}

__device__ __forceinline__ void cp16(const unsigned short* g, unsigned short* l) {
    // direct global->LDS, 16B per lane; LDS dest = wave-uniform base + lane*16
    __builtin_amdgcn_global_load_lds(
        (const __attribute__((address_space(1))) unsigned int*)g,
        (__attribute__((address_space(3))) unsigned int*)l,
        16, 0, 0);
}

// ---------- fp32 -> bf16 conversion ----------
__global__ void cvt_kernel(const float* __restrict__ src,
                           unsigned short* __restrict__ dst, int n4) {
    int i = blockIdx.x * blockDim.x + threadIdx.x;
    if (i >= n4) return;
    float4 v = ((const float4*)src)[i];
    ushort4 o;
    o.x = f2b(v.x); o.y = f2b(v.y); o.z = f2b(v.z); o.w = f2b(v.w);
    ((ushort4*)dst)[i] = o;
}

// ---------- gate: sigmoid scores, group-limited top-k, scatter to lists ----------
__global__ __launch_bounds__(256) void gate_kernel(
    const float* __restrict__ x, const float* __restrict__ gw,
    const float* __restrict__ gb,
    int* __restrict__ counts, int* __restrict__ lst, float* __restrict__ lstw)
{
    int tok  = blockIdx.x * 4 + (threadIdx.x >> 6);   // one wave per token
    int lane = threadIdx.x & 63;
    const float* xp = x + (size_t)tok * DIMD;
    float xv[16];
#pragma unroll
    for (int j = 0; j < 16; ++j) xv[j] = xp[j * 64 + lane];

    float sc[16];
#pragma unroll
    for (int e = 0; e < 16; ++e) {
        const float* gwe = gw + e * DIMD;
        float p = 0.f;
#pragma unroll
        for (int j = 0; j < 16; ++j) p += xv[j] * gwe[j * 64 + lane];
#pragma unroll
        for (int o = 32; o; o >>= 1) p += __shfl_xor(p, o, 64);
        sc[e] = p;
    }
    if (lane != 0) return;

    float orig[16], s[16];
#pragma unroll
    for (int e = 0; e < 16; ++e) {
        orig[e] = 1.f / (1.f + expf(-sc[e]));   // sigmoid
        s[e] = orig[e] + gb[e];                 // bias affects selection only
    }
    // group max (4 groups of 4)
    float gmax[4];
#pragma unroll
    for (int g = 0; g < 4; ++g) {
        float m = s[4 * g];
        for (int j = 1; j < 4; ++j) m = fmaxf(m, s[4 * g + j]);
        gmax[g] = m;
    }
    // top-2 groups, tie -> lower index (strict > matches lax.top_k)
    int g0 = 0;
    for (int g = 1; g < 4; ++g) if (gmax[g] > gmax[g0]) g0 = g;
    int g1 = -1;
    for (int g = 0; g < 4; ++g) { if (g == g0) continue; if (g1 < 0 || gmax[g] > gmax[g1]) g1 = g; }
    unsigned keep = (0xFu << (4 * g0)) | (0xFu << (4 * g1));
    unsigned used = 0;
    for (int j = 0; j < 4; ++j) {
        int best = -1;
        for (int e = 0; e < 16; ++e) {
            if (!((keep >> e) & 1u) || ((used >> e) & 1u)) continue;
            if (best < 0 || s[e] > s[best]) best = e;
        }
        used |= 1u << best;
        float w = orig[best] * 1.0f;            // ROUTE_SCALE = 1
        int pos = atomicAdd(&counts[best], 1);
        lst [best * T_TOK + pos] = tok;
        lstw[best * T_TOK + pos] = w;
    }
}

// ---------- GEMM1: H = silu(X W1^T) * (X W3^T) per expert, bf16 out ----------
__global__ __launch_bounds__(256, 2) void gemm1_kernel(
    const unsigned short* __restrict__ xb,
    const unsigned short* __restrict__ w1b,
    const unsigned short* __restrict__ w3b,
    const unsigned short* __restrict__ ws1b,
    const unsigned short* __restrict__ ws3b,
    const int* __restrict__ counts,
    const int* __restrict__ lst,
    unsigned short* __restrict__ H)
{
    const int e   = blockIdx.z;
    const int n_e = (e == NEXP) ? T_TOK : counts[e];
    const int m0  = blockIdx.x * 128;
    if (m0 >= n_e) return;
    const int n0  = blockIdx.y * 128;

    const unsigned short* w1p = (e == NEXP) ? ws1b : w1b + (size_t)e * INTERI * DIMD;
    const unsigned short* w3p = (e == NEXP) ? ws3b : w3b + (size_t)e * INTERI * DIMD;
    const int* lste = lst + e * T_TOK;

    __shared__ __align__(16) unsigned short lA [128 * 32];
    __shared__ __align__(16) unsigned short lB1[128 * 32];
    __shared__ __align__(16) unsigned short lB3[128 * 32];

    const int tid  = threadIdx.x;
    const int wave = tid >> 6;
    const int srow = tid >> 2;   // 0..63
    const int skg  = tid & 3;    // 0..3
    const int lane = tid & 63;

    // A gather rows (2 issues cover 128 rows)
    int r0 = m0 + srow, r1 = m0 + srow + 64;
    int t0, t1;
    if (e == NEXP) { t0 = (r0 < n_e) ? r0 : m0; t1 = (r1 < n_e) ? r1 : m0; }
    else           { t0 = lste[(r0 < n_e) ? r0 : m0]; t1 = lste[(r1 < n_e) ? r1 : m0]; }

    const unsigned short* gA0  = xb  + (size_t)t0 * DIMD + skg * 8;
    const unsigned short* gA1  = xb  + (size_t)t1 * DIMD + skg * 8;
    const unsigned short* gB1a = w1p + (size_t)(n0 + srow)      * DIMD + skg * 8;
    const unsigned short* gB1b = w1p + (size_t)(n0 + srow + 64) * DIMD + skg * 8;
    const unsigned short* gB3a = w3p + (size_t)(n0 + srow)      * DIMD + skg * 8;
    const unsigned short* gB3b = w3p + (size_t)(n0 + srow + 64) * DIMD + skg * 8;

    unsigned short* lA0  = &lA [wave * 512];
    unsigned short* lA1  = &lA [2048 + wave * 512];
    unsigned short* lB10 = &lB1[wave * 512];
    unsigned short* lB11 = &lB1[2048 + wave * 512];
    unsigned short* lB30 = &lB3[wave * 512];
    unsigned short* lB31 = &lB3[2048 + wave * 512];

    f32x4 acc1[4][4], acc3[4][4];
    const f32x4 zero = {0.f, 0.f, 0.f, 0.f};
#pragma unroll
    for (int i = 0; i < 4; ++i)
#pragma unroll
        for (int j = 0; j < 4; ++j) { acc1[i][j] = zero; acc3[i][j] = zero; }

    const int wr = (wave >> 1) * 64;
    const int wc = (wave & 1) * 64;
    const int quad = lane >> 4;
    const int lrow = lane & 15;

    for (int k0 = 0; k0 < DIMD; k0 += 32) {
        cp16(gA0  + k0, lA0);  cp16(gA1  + k0, lA1);
        cp16(gB1a + k0, lB10); cp16(gB1b + k0, lB11);
        cp16(gB3a + k0, lB30); cp16(gB3b + k0, lB31);
        __syncthreads();
        bf16x8 a[4], b1[4], b3[4];
#pragma unroll
        for (int t = 0; t < 4; ++t) {
            a[t]  = *(const bf16x8*)&lA [(wr + t * 16 + lrow) * 32 + quad * 8];
            b1[t] = *(const bf16x8*)&lB1[(wc + t * 16 + lrow) * 32 + quad * 8];
            b3[t] = *(const bf16x8*)&lB3[(wc + t * 16 + lrow) * 32 + quad * 8];
        }
#pragma unroll
        for (int i = 0; i < 4; ++i)
#pragma unroll
            for (int j = 0; j < 4; ++j) {
                acc1[i][j] = __builtin_amdgcn_mfma_f32_16x16x32_bf16(a[i], b1[j], acc1[i][j], 0, 0, 0);
                acc3[i][j] = __builtin_amdgcn_mfma_f32_16x16x32_bf16(a[i], b3[j], acc3[i][j], 0, 0, 0);
            }
        __syncthreads();
    }

    unsigned short* Hseg = H + (size_t)e * T_TOK * INTERI;
#pragma unroll
    for (int i = 0; i < 4; ++i) {
        int rbase = m0 + wr + i * 16 + quad * 4;
#pragma unroll
        for (int r = 0; r < 4; ++r) {
            int row = rbase + r;
            if (row >= n_e) continue;
            unsigned short* hrow = Hseg + (size_t)row * INTERI + n0 + wc + lrow;
#pragma unroll
            for (int j = 0; j < 4; ++j) {
                float v1 = acc1[i][j][r];
                float v3 = acc3[i][j][r];
                float hv = (v1 / (1.f + __expf(-v1))) * v3;   // silu(v1)*v3
                hrow[j * 16] = f2b(hv);
            }
        }
    }
}

// ---------- GEMM2: y += w * (H W2^T), weighted atomic combine ----------
__global__ __launch_bounds__(256, 3) void gemm2_kernel(
    const unsigned short* __restrict__ H,
    const unsigned short* __restrict__ w2b,
    const unsigned short* __restrict__ ws2b,
    const int* __restrict__ counts,
    const int* __restrict__ lst,
    const float* __restrict__ lstw,
    float* __restrict__ y)
{
    const int e   = blockIdx.z;
    const int n_e = (e == NEXP) ? T_TOK : counts[e];
    const int m0  = blockIdx.x * 128;
    if (m0 >= n_e) return;
    const int n0  = blockIdx.y * 128;

    const unsigned short* w2p  = (e == NEXP) ? ws2b : w2b + (size_t)e * DIMD * INTERI;
    const unsigned short* Hseg = H + (size_t)e * T_TOK * INTERI;

    __shared__ __align__(16) unsigned short lA[128 * 32];
    __shared__ __align__(16) unsigned short lB[128 * 32];

    const int tid  = threadIdx.x;
    const int wave = tid >> 6;
    const int srow = tid >> 2;
    const int skg  = tid & 3;
    const int lane = tid & 63;

    int ra0 = m0 + srow;       if (ra0 > n_e - 1) ra0 = n_e - 1;
    int ra1 = m0 + srow + 64;  if (ra1 > n_e - 1) ra1 = n_e - 1;

    const unsigned short* gA0 = Hseg + (size_t)ra0 * INTERI + skg * 8;
    const unsigned short* gA1 = Hseg + (size_t)ra1 * INTERI + skg * 8;
    const unsigned short* gB0 = w2p + (size_t)(n0 + srow)      * INTERI + skg * 8;
    const unsigned short* gB1 = w2p + (size_t)(n0 + srow + 64) * INTERI + skg * 8;

    unsigned short* lA0 = &lA[wave * 512];
    unsigned short* lA1 = &lA[2048 + wave * 512];
    unsigned short* lB0 = &lB[wave * 512];
    unsigned short* lB1p = &lB[2048 + wave * 512];

    f32x4 acc[4][4];
    const f32x4 zero = {0.f, 0.f, 0.f, 0.f};
#pragma unroll
    for (int i = 0; i < 4; ++i)
#pragma unroll
        for (int j = 0; j < 4; ++j) acc[i][j] = zero;

    const int wr = (wave >> 1) * 64;
    const int wc = (wave & 1) * 64;
    const int quad = lane >> 4;
    const int lrow = lane & 15;

    for (int k0 = 0; k0 < INTERI; k0 += 32) {
        cp16(gA0 + k0, lA0); cp16(gA1 + k0, lA1);
        cp16(gB0 + k0, lB0); cp16(gB1 + k0, lB1p);
        __syncthreads();
        bf16x8 a[4], b[4];
#pragma unroll
        for (int t = 0; t < 4; ++t) {
            a[t] = *(const bf16x8*)&lA[(wr + t * 16 + lrow) * 32 + quad * 8];
            b[t] = *(const bf16x8*)&lB[(wc + t * 16 + lrow) * 32 + quad * 8];
        }
#pragma unroll
        for (int i = 0; i < 4; ++i)
#pragma unroll
            for (int j = 0; j < 4; ++j)
                acc[i][j] = __builtin_amdgcn_mfma_f32_16x16x32_bf16(a[i], b[j], acc[i][j], 0, 0, 0);
        __syncthreads();
    }

#pragma unroll
    for (int i = 0; i < 4; ++i) {
        int rbase = m0 + wr + i * 16 + quad * 4;
#pragma unroll
        for (int r = 0; r < 4; ++r) {
            int row = rbase + r;
            if (row >= n_e) continue;
            int tok; float wt;
            if (e == NEXP) { tok = row; wt = 1.f; }
            else { tok = lst[e * T_TOK + row]; wt = lstw[e * T_TOK + row]; }
            float* yrow = y + (size_t)tok * DIMD + n0 + wc + lrow;
#pragma unroll
            for (int j = 0; j < 4; ++j)
                atomicAdd(&yrow[j * 16], wt * acc[i][j][r]);
        }
    }
}

// ---------- launcher ----------
extern "C" void kernel_launch(void* const* d_in, const int* in_sizes, int n_in,
                              void* d_out, int out_size, void* d_ws, size_t ws_size,
                              hipStream_t stream)
{
    const float* x   = (const float*)d_in[0];
    const float* gw  = (const float*)d_in[1];
    const float* gb  = (const float*)d_in[2];
    const float* w1  = (const float*)d_in[3];
    const float* w2  = (const float*)d_in[4];
    const float* w3  = (const float*)d_in[5];
    const float* ws1 = (const float*)d_in[6];
    const float* ws2 = (const float*)d_in[7];
    const float* ws3 = (const float*)d_in[8];

    char* base = (char*)d_ws;
    size_t off = 0;
    auto alloc = [&](size_t bytes) {
        char* q = base + off; off += (bytes + 255) & ~(size_t)255; return q;
    };
    unsigned short* xb   = (unsigned short*)alloc((size_t)T_TOK * DIMD * 2);
    unsigned short* w1b  = (unsigned short*)alloc((size_t)NEXP * INTERI * DIMD * 2);
    unsigned short* w3b  = (unsigned short*)alloc((size_t)NEXP * INTERI * DIMD * 2);
    unsigned short* w2b  = (unsigned short*)alloc((size_t)NEXP * DIMD * INTERI * 2);
    unsigned short* ws1b = (unsigned short*)alloc((size_t)INTERI * DIMD * 2);
    unsigned short* ws3b = (unsigned short*)alloc((size_t)INTERI * DIMD * 2);
    unsigned short* ws2b = (unsigned short*)alloc((size_t)DIMD * INTERI * 2);
    unsigned short* Hb   = (unsigned short*)alloc((size_t)NSEG * T_TOK * INTERI * 2);
    int*            cnts = (int*)alloc(NEXP * 4);
    int*            lstp = (int*)alloc((size_t)NEXP * T_TOK * 4);
    float*          lstw = (float*)alloc((size_t)NEXP * T_TOK * 4);

    hipMemsetAsync(cnts, 0, NEXP * 4, stream);
    hipMemsetAsync(d_out, 0, (size_t)T_TOK * DIMD * 4, stream);

    auto cvt = [&](const float* s, unsigned short* d, size_t n) {
        int n4 = (int)(n / 4);
        cvt_kernel<<<(n4 + 255) / 256, 256, 0, stream>>>(s, d, n4);
    };
    cvt(x,   xb,   (size_t)T_TOK * DIMD);
    cvt(w1,  w1b,  (size_t)NEXP * INTERI * DIMD);
    cvt(w3,  w3b,  (size_t)NEXP * INTERI * DIMD);
    cvt(w2,  w2b,  (size_t)NEXP * DIMD * INTERI);
    cvt(ws1, ws1b, (size_t)INTERI * DIMD);
    cvt(ws3, ws3b, (size_t)INTERI * DIMD);
    cvt(ws2, ws2b, (size_t)DIMD * INTERI);

    gate_kernel<<<T_TOK / 4, 256, 0, stream>>>(x, gw, gb, cnts, lstp, lstw);
    gemm1_kernel<<<dim3(16, 4, NSEG), 256, 0, stream>>>(xb, w1b, w3b, ws1b, ws3b, cnts, lstp, Hb);
    gemm2_kernel<<<dim3(16, 8, NSEG), 256, 0, stream>>>(Hb, w2b, ws2b, cnts, lstp, lstw, (float*)d_out);
}